// Round 8
// baseline (370.784 us; speedup 1.0000x reference)
//
#include <hip/hip_runtime.h>

// ---------------------------------------------------------------------------
// TopoTransform: batched sign-fixed QR (MGS) + per-site channel mix.
//   problem 0: B=32, C=64,  S=784   problem 1: B=32, C=256, S=196
//   out[b][c][s] = sum_k Q[s][c][k] * x[b][k][s],  Q[s] = qr(W[s]) sign-fixed
// MGS yields R[j][j] > 0 directly => Q already sign-fixed.
//
// R8: pack the two independent per-thread column chains (col0,col1) into
// float2 and use __builtin_elementwise_fma -> v_pk_fma_f32 (VOP3P, 2 FMA/
// instr). R7 evidence: kernel is ~half VALU-issue-bound (336K cyc of 700K);
// conflicts/CSE fixes were nulls (hidden). Packing cuts dot 32->16,
// update 32->16, apply 8->4 instructions per round while keeping each
// half-chain's operation sequence BIT-IDENTICAL (fma per element, same
// order) -> absmax must stay exactly 0.09765625. Spill sentinel: WRITE_SIZE
// must stay 6272 KB.
// ---------------------------------------------------------------------------

static constexpr int BB = 32;  // batch

typedef float v2f __attribute__((ext_vector_type(2)));

__device__ __forceinline__ v2f sp2(float x) { v2f r; r.x = x; r.y = x; return r; }
__device__ __forceinline__ v2f fma2(v2f a, v2f b, v2f c) {
    return __builtin_elementwise_fma(a, b, c);
}

// -------- DPP 16-lane all-reduce (sum) on the VALU pipe --------------------
template<int CTRL>
__device__ __forceinline__ float dpp_add(float x) {
    int y = __builtin_amdgcn_update_dpp(0, __float_as_int(x), CTRL, 0xF, 0xF, false);
    return x + __int_as_float(y);
}
__device__ __forceinline__ float rowred16(float p) {
    p = dpp_add<0x128>(p);  // row_ror:8
    p = dpp_add<0x124>(p);  // row_ror:4
    p = dpp_add<0x122>(p);  // row_ror:2
    p = dpp_add<0x121>(p);  // row_ror:1
    return p;               // all 16 lanes of the row hold the sum
}

// qpan slot layout (1KB per col j): row r = r16*16 + 4g + e stored at
// float idx j*256 + g*64 + ((r16 ^ 2g) << 2) + e.
__device__ __forceinline__ int qoff(int j, int g, int r16) {
    return j * 256 + g * 64 + ((r16 ^ (2 * g)) << 2);
}

// -------- transpose: in (R, S) row-major -> out (S, R) row-major ----------
__global__ __launch_bounds__(256) void tkern(const float* __restrict__ in,
                                             float* __restrict__ out,
                                             int R, int S) {
    __shared__ float tile[32][33];
    const int tx = threadIdx.x, ty = threadIdx.y;
    const int s0 = blockIdx.x * 32, r0 = blockIdx.y * 32;
    #pragma unroll
    for (int i = ty; i < 32; i += 8) {
        int r = r0 + i, s = s0 + tx;
        tile[i][tx] = (r < R && s < S) ? in[(size_t)r * S + s] : 0.f;
    }
    __syncthreads();
    #pragma unroll
    for (int i = ty; i < 32; i += 8) {
        int s = s0 + i, r = r0 + tx;
        if (s < S && r < R) out[(size_t)s * R + r] = tile[tx][i];
    }
}

// ===========================================================================
// C=64 path: unchanged (register-resident MGS + chunked apply).
// ===========================================================================
template<int C, int CT, int KC>
__device__ __forceinline__ void qr_body(const float* __restrict__ W,
                                        float* __restrict__ XY) {
    constexpr int RT = 16;
    constexpr int TR = C / RT;
    constexpr int THREADS = RT * CT;
    constexpr int QSTR = TR + 4;
    constexpr int XSTR = C + 4;

    const int s  = blockIdx.x;
    const int t  = threadIdx.x;
    const int rb = t & 15;
    const int cb = t >> 4;

    __shared__ float qs[2][RT * QSTR];
    __shared__ float xs[BB * XSTR];
    __shared__ float qc[KC * C];

    float a[TR][4];
    {
        const float* Wp = W + (size_t)s * C * C + (size_t)(rb * TR) * C + cb * 4;
        #pragma unroll
        for (int i = 0; i < TR; ++i) {
            float4 v = *reinterpret_cast<const float4*>(Wp + (size_t)i * C);
            a[i][0] = v.x; a[i][1] = v.y; a[i][2] = v.z; a[i][3] = v.w;
        }
    }
    {
        const float* Xp = XY + (size_t)s * BB * C;
        #pragma unroll
        for (int v = 0; v < (BB * C) / (4 * THREADS); ++v) {
            int idx = 4 * (t + v * THREADS);
            int b = idx / C, k = idx % C;
            float4 x4 = *reinterpret_cast<const float4*>(Xp + idx);
            *reinterpret_cast<float4*>(&xs[b * XSTR + k]) = x4;
        }
    }

    int buf = 0;
    #pragma unroll 1
    for (int j = 0; j < C; ++j) {
        const int cbj = j >> 2, jj = j & 3;
        if (cb == cbj) {
            #pragma unroll
            for (int q = 0; q < 4; ++q) {
                if (q == jj) {
                    float p = 0.f;
                    #pragma unroll
                    for (int i = 0; i < TR; ++i) p += a[i][q] * a[i][q];
                    p = rowred16(p);
                    const float rn = 1.0f / sqrtf(p);
                    #pragma unroll
                    for (int i = 0; i < TR; ++i) a[i][q] *= rn;
                    #pragma unroll
                    for (int i = 0; i < TR; i += 4) {
                        *reinterpret_cast<float4*>(&qs[buf][rb * QSTR + i]) =
                            make_float4(a[i][q], a[i+1][q], a[i+2][q], a[i+3][q]);
                    }
                }
            }
        }
        __syncthreads();
        if (cb * 4 + 3 > j) {
            float qv[TR];
            #pragma unroll
            for (int i = 0; i < TR; i += 4) {
                float4 v = *reinterpret_cast<const float4*>(&qs[buf][rb * QSTR + i]);
                qv[i] = v.x; qv[i+1] = v.y; qv[i+2] = v.z; qv[i+3] = v.w;
            }
            #pragma unroll
            for (int q = 0; q < 4; ++q) {
                if (cb * 4 + q > j) {
                    float p = 0.f;
                    #pragma unroll
                    for (int i = 0; i < TR; ++i) p += a[i][q] * qv[i];
                    p = rowred16(p);
                    #pragma unroll
                    for (int i = 0; i < TR; ++i) a[i][q] -= p * qv[i];
                }
            }
        }
        buf ^= 1;
    }

    const int u  = t % (C / 4);
    const int bp = t / (C / 4);
    float acc[2][4] = {{0,0,0,0},{0,0,0,0}};

    #pragma unroll 1
    for (int ch = 0; ch < C / KC; ++ch) {
        __syncthreads();
        if (cb >= (ch * KC) / 4 && cb < ((ch + 1) * KC) / 4) {
            #pragma unroll
            for (int q = 0; q < 4; ++q) {
                const int kk = cb * 4 + q - ch * KC;
                const int swz = (kk & 7) << 2;
                #pragma unroll
                for (int i = 0; i < TR; i += 4) {
                    const int cout = rb * TR + i;
                    *reinterpret_cast<float4*>(&qc[kk * C + (cout ^ swz)]) =
                        make_float4(a[i][q], a[i+1][q], a[i+2][q], a[i+3][q]);
                }
            }
        }
        __syncthreads();
        #pragma unroll
        for (int kk = 0; kk < KC; kk += 4) {
            const int k = ch * KC + kk;
            float4 x0 = *reinterpret_cast<const float4*>(&xs[(2*bp    ) * XSTR + k]);
            float4 x1 = *reinterpret_cast<const float4*>(&xs[(2*bp + 1) * XSTR + k]);
            #pragma unroll
            for (int m = 0; m < 4; ++m) {
                const int swz = ((kk + m) & 7) << 2;
                float4 qv4 = *reinterpret_cast<const float4*>(&qc[(kk + m) * C + ((4 * u) ^ swz)]);
                const float xa = (&x0.x)[m], xb = (&x1.x)[m];
                acc[0][0] += xa * qv4.x; acc[0][1] += xa * qv4.y;
                acc[0][2] += xa * qv4.z; acc[0][3] += xa * qv4.w;
                acc[1][0] += xb * qv4.x; acc[1][1] += xb * qv4.y;
                acc[1][2] += xb * qv4.z; acc[1][3] += xb * qv4.w;
            }
        }
    }
    {
        float* Yp = XY + (size_t)s * BB * C;
        *reinterpret_cast<float4*>(Yp + (2*bp    ) * C + 4 * u) =
            make_float4(acc[0][0], acc[0][1], acc[0][2], acc[0][3]);
        *reinterpret_cast<float4*>(Yp + (2*bp + 1) * C + 4 * u) =
            make_float4(acc[1][0], acc[1][1], acc[1][2], acc[1][3]);
    }
}

__global__ __launch_bounds__(256) void qr64(const float* __restrict__ W,
                                            float* __restrict__ XY) {
    qr_body<64, 16, 64>(W, XY);
}

// ===========================================================================
// C=256 left-looking 2-panel MGS, 1024 threads, packed-fp32 chains.
//   a2[i] = (col0[i], col1[i]);  y2[e] = (y_row2v[e], y_row2v+1[e])
// ===========================================================================
__device__ __forceinline__ void panel_mgs(v2f (&a2)[16], v2f (&y2)[4],
                                          float* qpan, const float* xsb,
                                          int rb, int cb, int u, int v) {
    #pragma unroll 1
    for (int j = 0; j < 128; ++j) {
        if (cb == (j >> 1)) {
            if ((j & 1) == 0) {   // static .x/.y selection (rule #20)
                float p = 0.f;
                #pragma unroll
                for (int i = 0; i < 16; ++i) p += a2[i].x * a2[i].x;
                p = rowred16(p);
                const float rn = 1.0f / sqrtf(p);
                #pragma unroll
                for (int i = 0; i < 16; ++i) a2[i].x *= rn;
                #pragma unroll
                for (int g = 0; g < 4; ++g) {
                    *reinterpret_cast<float4*>(&qpan[qoff(j, g, rb)]) =
                        make_float4(a2[4*g].x, a2[4*g+1].x, a2[4*g+2].x, a2[4*g+3].x);
                }
            } else {
                float p = 0.f;
                #pragma unroll
                for (int i = 0; i < 16; ++i) p += a2[i].y * a2[i].y;
                p = rowred16(p);
                const float rn = 1.0f / sqrtf(p);
                #pragma unroll
                for (int i = 0; i < 16; ++i) a2[i].y *= rn;
                #pragma unroll
                for (int g = 0; g < 4; ++g) {
                    *reinterpret_cast<float4*>(&qpan[qoff(j, g, rb)]) =
                        make_float4(a2[4*g].y, a2[4*g+1].y, a2[4*g+2].y, a2[4*g+3].y);
                }
            }
        }
        __syncthreads();
        const bool act1 = (2*cb + 1 > j);
        const bool act0 = (2*cb > j);
        if (act1) {   // row-uniform guard: DPP rows stay converged
            const float4 q40 = *reinterpret_cast<const float4*>(&qpan[qoff(j, 0, rb)]);
            const float4 q41 = *reinterpret_cast<const float4*>(&qpan[qoff(j, 1, rb)]);
            const float4 q42 = *reinterpret_cast<const float4*>(&qpan[qoff(j, 2, rb)]);
            const float4 q43 = *reinterpret_cast<const float4*>(&qpan[qoff(j, 3, rb)]);
            v2f p01 = {0.f, 0.f};
            p01 = fma2(a2[ 0], sp2(q40.x), p01);
            p01 = fma2(a2[ 1], sp2(q40.y), p01);
            p01 = fma2(a2[ 2], sp2(q40.z), p01);
            p01 = fma2(a2[ 3], sp2(q40.w), p01);
            p01 = fma2(a2[ 4], sp2(q41.x), p01);
            p01 = fma2(a2[ 5], sp2(q41.y), p01);
            p01 = fma2(a2[ 6], sp2(q41.z), p01);
            p01 = fma2(a2[ 7], sp2(q41.w), p01);
            p01 = fma2(a2[ 8], sp2(q42.x), p01);
            p01 = fma2(a2[ 9], sp2(q42.y), p01);
            p01 = fma2(a2[10], sp2(q42.z), p01);
            p01 = fma2(a2[11], sp2(q42.w), p01);
            p01 = fma2(a2[12], sp2(q43.x), p01);
            p01 = fma2(a2[13], sp2(q43.y), p01);
            p01 = fma2(a2[14], sp2(q43.z), p01);
            p01 = fma2(a2[15], sp2(q43.w), p01);
            const float p0 = rowred16(p01.x);
            const float p1 = rowred16(p01.y);
            if (act0) {
                v2f pp; pp.x = p0; pp.y = p1;
                a2[ 0] = fma2(-pp, sp2(q40.x), a2[ 0]);
                a2[ 1] = fma2(-pp, sp2(q40.y), a2[ 1]);
                a2[ 2] = fma2(-pp, sp2(q40.z), a2[ 2]);
                a2[ 3] = fma2(-pp, sp2(q40.w), a2[ 3]);
                a2[ 4] = fma2(-pp, sp2(q41.x), a2[ 4]);
                a2[ 5] = fma2(-pp, sp2(q41.y), a2[ 5]);
                a2[ 6] = fma2(-pp, sp2(q41.z), a2[ 6]);
                a2[ 7] = fma2(-pp, sp2(q41.w), a2[ 7]);
                a2[ 8] = fma2(-pp, sp2(q42.x), a2[ 8]);
                a2[ 9] = fma2(-pp, sp2(q42.y), a2[ 9]);
                a2[10] = fma2(-pp, sp2(q42.z), a2[10]);
                a2[11] = fma2(-pp, sp2(q42.w), a2[11]);
                a2[12] = fma2(-pp, sp2(q43.x), a2[12]);
                a2[13] = fma2(-pp, sp2(q43.y), a2[13]);
                a2[14] = fma2(-pp, sp2(q43.z), a2[14]);
                a2[15] = fma2(-pp, sp2(q43.w), a2[15]);
            } else {
                // only col1 active (owner's local round): scalar .y updates
                a2[ 0].y -= p1 * q40.x; a2[ 1].y -= p1 * q40.y;
                a2[ 2].y -= p1 * q40.z; a2[ 3].y -= p1 * q40.w;
                a2[ 4].y -= p1 * q41.x; a2[ 5].y -= p1 * q41.y;
                a2[ 6].y -= p1 * q41.z; a2[ 7].y -= p1 * q41.w;
                a2[ 8].y -= p1 * q42.x; a2[ 9].y -= p1 * q42.y;
                a2[10].y -= p1 * q42.z; a2[11].y -= p1 * q42.w;
                a2[12].y -= p1 * q43.x; a2[13].y -= p1 * q43.y;
                a2[14].y -= p1 * q43.z; a2[15].y -= p1 * q43.w;
            }
        }
        {   // fused rank-1 apply: y += x[b,j] * q_j[c]   (j ascending)
            float4 q4 = *reinterpret_cast<const float4*>(
                &qpan[qoff(j, u & 3, u >> 2)]);
            v2f xab; xab.x = xsb[j*33 + 2*v]; xab.y = xsb[j*33 + 2*v + 1];
            y2[0] = fma2(xab, sp2(q4.x), y2[0]);
            y2[1] = fma2(xab, sp2(q4.y), y2[1]);
            y2[2] = fma2(xab, sp2(q4.z), y2[2]);
            y2[3] = fma2(xab, sp2(q4.w), y2[3]);
        }
    }
}

__global__ __launch_bounds__(1024) void qr256ll(const float* __restrict__ W,
                                                float* __restrict__ XY) {
    __shared__ float qpan[128 * 256];   // 128 KiB: finished q's, 1KB/col slot
    __shared__ float xsb[128 * 33];     // 16.5 KiB: X panel [col][b], pad 33

    const int s  = blockIdx.x;
    const int t  = threadIdx.x;
    const int rb = t & 15;
    const int cb = t >> 4;
    const int u  = t & 63;
    const int v  = t >> 6;

    const float* Wp = W + (size_t)s * 65536;
    float* Xp = XY + (size_t)s * 8192;

    v2f a2[16];
    v2f y2[4]; y2[0] = sp2(0.f); y2[1] = sp2(0.f); y2[2] = sp2(0.f); y2[3] = sp2(0.f);

    // ---- panel 0: load W cols [0,128) + stage X cols [0,128) ----
    #pragma unroll
    for (int i = 0; i < 16; ++i)
        a2[i] = *reinterpret_cast<const v2f*>(Wp + (size_t)(rb*16 + i) * 256 + 2*cb);
    {
        const int tj = t & 127, tb = t >> 7;
        #pragma unroll
        for (int d = 0; d < 4; ++d)
            xsb[tj*33 + 4*tb + d] = Xp[(4*tb + d)*256 + tj];
    }
    __syncthreads();

    panel_mgs(a2, y2, qpan, xsb, rb, cb, u, v);

    // ---- glue: reload regs with W cols [128,256), restage X, cross-pass ----
    __syncthreads();   // panel-0 consumers done before xsb is overwritten
    #pragma unroll
    for (int i = 0; i < 16; ++i)
        a2[i] = *reinterpret_cast<const v2f*>(Wp + (size_t)(rb*16 + i) * 256 + 128 + 2*cb);
    {
        const int tj = t & 127, tb = t >> 7;
        #pragma unroll
        for (int d = 0; d < 4; ++d)
            xsb[tj*33 + 4*tb + d] = Xp[(4*tb + d)*256 + 128 + tj];
    }
    // cross-pass: orthogonalize both register cols vs Q0 (barrier-free;
    // qpan read-only here, xsb writes touch a disjoint region)
    #pragma unroll 1
    for (int k = 0; k < 128; ++k) {
        const float4 q40 = *reinterpret_cast<const float4*>(&qpan[qoff(k, 0, rb)]);
        const float4 q41 = *reinterpret_cast<const float4*>(&qpan[qoff(k, 1, rb)]);
        const float4 q42 = *reinterpret_cast<const float4*>(&qpan[qoff(k, 2, rb)]);
        const float4 q43 = *reinterpret_cast<const float4*>(&qpan[qoff(k, 3, rb)]);
        v2f p01 = {0.f, 0.f};
        p01 = fma2(a2[ 0], sp2(q40.x), p01);
        p01 = fma2(a2[ 1], sp2(q40.y), p01);
        p01 = fma2(a2[ 2], sp2(q40.z), p01);
        p01 = fma2(a2[ 3], sp2(q40.w), p01);
        p01 = fma2(a2[ 4], sp2(q41.x), p01);
        p01 = fma2(a2[ 5], sp2(q41.y), p01);
        p01 = fma2(a2[ 6], sp2(q41.z), p01);
        p01 = fma2(a2[ 7], sp2(q41.w), p01);
        p01 = fma2(a2[ 8], sp2(q42.x), p01);
        p01 = fma2(a2[ 9], sp2(q42.y), p01);
        p01 = fma2(a2[10], sp2(q42.z), p01);
        p01 = fma2(a2[11], sp2(q42.w), p01);
        p01 = fma2(a2[12], sp2(q43.x), p01);
        p01 = fma2(a2[13], sp2(q43.y), p01);
        p01 = fma2(a2[14], sp2(q43.z), p01);
        p01 = fma2(a2[15], sp2(q43.w), p01);
        const float p0 = rowred16(p01.x);
        const float p1 = rowred16(p01.y);
        v2f pp; pp.x = p0; pp.y = p1;
        a2[ 0] = fma2(-pp, sp2(q40.x), a2[ 0]);
        a2[ 1] = fma2(-pp, sp2(q40.y), a2[ 1]);
        a2[ 2] = fma2(-pp, sp2(q40.z), a2[ 2]);
        a2[ 3] = fma2(-pp, sp2(q40.w), a2[ 3]);
        a2[ 4] = fma2(-pp, sp2(q41.x), a2[ 4]);
        a2[ 5] = fma2(-pp, sp2(q41.y), a2[ 5]);
        a2[ 6] = fma2(-pp, sp2(q41.z), a2[ 6]);
        a2[ 7] = fma2(-pp, sp2(q41.w), a2[ 7]);
        a2[ 8] = fma2(-pp, sp2(q42.x), a2[ 8]);
        a2[ 9] = fma2(-pp, sp2(q42.y), a2[ 9]);
        a2[10] = fma2(-pp, sp2(q42.z), a2[10]);
        a2[11] = fma2(-pp, sp2(q42.w), a2[11]);
        a2[12] = fma2(-pp, sp2(q43.x), a2[12]);
        a2[13] = fma2(-pp, sp2(q43.y), a2[13]);
        a2[14] = fma2(-pp, sp2(q43.z), a2[14]);
        a2[15] = fma2(-pp, sp2(q43.w), a2[15]);
    }
    __syncthreads();   // xsb staged + cross-pass complete everywhere

    // ---- panel 1 (qpan slots reused; Q0 no longer needed) ----
    panel_mgs(a2, y2, qpan, xsb, rb, cb, u, v);

    // ---- write Y in place over X (coalesced float4) ----
    *reinterpret_cast<float4*>(Xp + (size_t)(2*v    )*256 + 4*u) =
        make_float4(y2[0].x, y2[1].x, y2[2].x, y2[3].x);
    *reinterpret_cast<float4*>(Xp + (size_t)(2*v + 1)*256 + 4*u) =
        make_float4(y2[0].y, y2[1].y, y2[2].y, y2[3].y);
}

extern "C" void kernel_launch(void* const* d_in, const int* in_sizes, int n_in,
                              void* d_out, int out_size, void* d_ws, size_t ws_size,
                              hipStream_t stream) {
    (void)in_sizes; (void)n_in; (void)out_size; (void)ws_size;
    const float* x0 = (const float*)d_in[0];  // (32, 64, 784)
    const float* x1 = (const float*)d_in[1];  // (32, 256, 196)
    const float* W0 = (const float*)d_in[2];  // (784, 64, 64)
    const float* W1 = (const float*)d_in[3];  // (196, 256, 256)
    float* y0  = (float*)d_out;               // (32, 64, 784) flat
    float* y1  = y0 + 1605632;                // (32, 256, 196) flat
    float* xt0 = (float*)d_ws;                // (784, 32*64)
    float* xt1 = xt0 + 1605632;               // (196, 32*256)

    dim3 tb(32, 8);
    // x (B*C, S) -> xt (S, B*C)
    tkern<<<dim3(25,  64), tb, 0, stream>>>(x0, xt0, 2048, 784);
    tkern<<<dim3(7,  256), tb, 0, stream>>>(x1, xt1, 8192, 196);
    // fused QR + apply (Y overwrites xt in place)
    qr64   <<<784,  256, 0, stream>>>(W0, xt0);
    qr256ll<<<196, 1024, 0, stream>>>(W1, xt1);
    // xt (S, B*C) -> y (B*C, S)
    tkern<<<dim3(64,  25), tb, 0, stream>>>(xt0, y0, 784, 2048);
    tkern<<<dim3(256,  7), tb, 0, stream>>>(xt1, y1, 196, 8192);
}

// Round 9
// 290.295 us; speedup vs baseline: 1.2773x; 1.2773x over previous
//
#include <hip/hip_runtime.h>

// ---------------------------------------------------------------------------
// TopoTransform: batched sign-fixed QR (MGS) + per-site channel mix.
//   problem 0: B=32, C=64,  S=784   problem 1: B=32, C=256, S=196
//   out[b][c][s] = sum_k Q[s][c][k] * x[b][k][s],  Q[s] = qr(W[s]) sign-fixed
// MGS yields R[j][j] > 0 directly => Q already sign-fixed.
//
// R9: revert R8's packed fp32 (regressed: splat movs + VGPR ceiling). Keep
// R7 scalar arithmetic but retire TWO columns per barrier round: group cb
// owns cols {2cb,2cb+1}; the NEXT owner finishes its pair fully in-registers
// (norm .x -> orth .y vs .x-regs -> norm .y, write both qpan slots) at the
// end of round m, hidden under the other waves' 2-q dot/update. Barriers
// 258 -> ~132. R7 evidence: ~940 cyc/round of lockstep convoy stall (48%
// VALUBusy, 1800 cyc/round) -- halving rounds attacks exactly that.
// Every FMA/reduce chain keeps R7's op order -> absmax must stay EXACTLY
// 0.09765625; WRITE_SIZE must stay 6272 KB (spill sentinel).
// ---------------------------------------------------------------------------

static constexpr int BB = 32;  // batch

// -------- DPP 16-lane all-reduce (sum) on the VALU pipe --------------------
template<int CTRL>
__device__ __forceinline__ float dpp_add(float x) {
    int y = __builtin_amdgcn_update_dpp(0, __float_as_int(x), CTRL, 0xF, 0xF, false);
    return x + __int_as_float(y);
}
__device__ __forceinline__ float rowred16(float p) {
    p = dpp_add<0x128>(p);  // row_ror:8
    p = dpp_add<0x124>(p);  // row_ror:4
    p = dpp_add<0x122>(p);  // row_ror:2
    p = dpp_add<0x121>(p);  // row_ror:1
    return p;               // all 16 lanes of the row hold the sum
}

// qpan slot layout (1KB per col j): row r = r16*16 + 4g + e stored at
// float idx j*256 + g*64 + ((r16 ^ 2g) << 2) + e.
__device__ __forceinline__ int qoff(int j, int g, int r16) {
    return j * 256 + g * 64 + ((r16 ^ (2 * g)) << 2);
}

// -------- transpose: in (R, S) row-major -> out (S, R) row-major ----------
__global__ __launch_bounds__(256) void tkern(const float* __restrict__ in,
                                             float* __restrict__ out,
                                             int R, int S) {
    __shared__ float tile[32][33];
    const int tx = threadIdx.x, ty = threadIdx.y;
    const int s0 = blockIdx.x * 32, r0 = blockIdx.y * 32;
    #pragma unroll
    for (int i = ty; i < 32; i += 8) {
        int r = r0 + i, s = s0 + tx;
        tile[i][tx] = (r < R && s < S) ? in[(size_t)r * S + s] : 0.f;
    }
    __syncthreads();
    #pragma unroll
    for (int i = ty; i < 32; i += 8) {
        int s = s0 + i, r = r0 + tx;
        if (s < S && r < R) out[(size_t)s * R + r] = tile[tx][i];
    }
}

// ===========================================================================
// C=64 path: unchanged (register-resident MGS + chunked apply).
// ===========================================================================
template<int C, int CT, int KC>
__device__ __forceinline__ void qr_body(const float* __restrict__ W,
                                        float* __restrict__ XY) {
    constexpr int RT = 16;
    constexpr int TR = C / RT;
    constexpr int THREADS = RT * CT;
    constexpr int QSTR = TR + 4;
    constexpr int XSTR = C + 4;

    const int s  = blockIdx.x;
    const int t  = threadIdx.x;
    const int rb = t & 15;
    const int cb = t >> 4;

    __shared__ float qs[2][RT * QSTR];
    __shared__ float xs[BB * XSTR];
    __shared__ float qc[KC * C];

    float a[TR][4];
    {
        const float* Wp = W + (size_t)s * C * C + (size_t)(rb * TR) * C + cb * 4;
        #pragma unroll
        for (int i = 0; i < TR; ++i) {
            float4 v = *reinterpret_cast<const float4*>(Wp + (size_t)i * C);
            a[i][0] = v.x; a[i][1] = v.y; a[i][2] = v.z; a[i][3] = v.w;
        }
    }
    {
        const float* Xp = XY + (size_t)s * BB * C;
        #pragma unroll
        for (int v = 0; v < (BB * C) / (4 * THREADS); ++v) {
            int idx = 4 * (t + v * THREADS);
            int b = idx / C, k = idx % C;
            float4 x4 = *reinterpret_cast<const float4*>(Xp + idx);
            *reinterpret_cast<float4*>(&xs[b * XSTR + k]) = x4;
        }
    }

    int buf = 0;
    #pragma unroll 1
    for (int j = 0; j < C; ++j) {
        const int cbj = j >> 2, jj = j & 3;
        if (cb == cbj) {
            #pragma unroll
            for (int q = 0; q < 4; ++q) {
                if (q == jj) {
                    float p = 0.f;
                    #pragma unroll
                    for (int i = 0; i < TR; ++i) p += a[i][q] * a[i][q];
                    p = rowred16(p);
                    const float rn = 1.0f / sqrtf(p);
                    #pragma unroll
                    for (int i = 0; i < TR; ++i) a[i][q] *= rn;
                    #pragma unroll
                    for (int i = 0; i < TR; i += 4) {
                        *reinterpret_cast<float4*>(&qs[buf][rb * QSTR + i]) =
                            make_float4(a[i][q], a[i+1][q], a[i+2][q], a[i+3][q]);
                    }
                }
            }
        }
        __syncthreads();
        if (cb * 4 + 3 > j) {
            float qv[TR];
            #pragma unroll
            for (int i = 0; i < TR; i += 4) {
                float4 v = *reinterpret_cast<const float4*>(&qs[buf][rb * QSTR + i]);
                qv[i] = v.x; qv[i+1] = v.y; qv[i+2] = v.z; qv[i+3] = v.w;
            }
            #pragma unroll
            for (int q = 0; q < 4; ++q) {
                if (cb * 4 + q > j) {
                    float p = 0.f;
                    #pragma unroll
                    for (int i = 0; i < TR; ++i) p += a[i][q] * qv[i];
                    p = rowred16(p);
                    #pragma unroll
                    for (int i = 0; i < TR; ++i) a[i][q] -= p * qv[i];
                }
            }
        }
        buf ^= 1;
    }

    const int u  = t % (C / 4);
    const int bp = t / (C / 4);
    float acc[2][4] = {{0,0,0,0},{0,0,0,0}};

    #pragma unroll 1
    for (int ch = 0; ch < C / KC; ++ch) {
        __syncthreads();
        if (cb >= (ch * KC) / 4 && cb < ((ch + 1) * KC) / 4) {
            #pragma unroll
            for (int q = 0; q < 4; ++q) {
                const int kk = cb * 4 + q - ch * KC;
                const int swz = (kk & 7) << 2;
                #pragma unroll
                for (int i = 0; i < TR; i += 4) {
                    const int cout = rb * TR + i;
                    *reinterpret_cast<float4*>(&qc[kk * C + (cout ^ swz)]) =
                        make_float4(a[i][q], a[i+1][q], a[i+2][q], a[i+3][q]);
                }
            }
        }
        __syncthreads();
        #pragma unroll
        for (int kk = 0; kk < KC; kk += 4) {
            const int k = ch * KC + kk;
            float4 x0 = *reinterpret_cast<const float4*>(&xs[(2*bp    ) * XSTR + k]);
            float4 x1 = *reinterpret_cast<const float4*>(&xs[(2*bp + 1) * XSTR + k]);
            #pragma unroll
            for (int m = 0; m < 4; ++m) {
                const int swz = ((kk + m) & 7) << 2;
                float4 qv4 = *reinterpret_cast<const float4*>(&qc[(kk + m) * C + ((4 * u) ^ swz)]);
                const float xa = (&x0.x)[m], xb = (&x1.x)[m];
                acc[0][0] += xa * qv4.x; acc[0][1] += xa * qv4.y;
                acc[0][2] += xa * qv4.z; acc[0][3] += xa * qv4.w;
                acc[1][0] += xb * qv4.x; acc[1][1] += xb * qv4.y;
                acc[1][2] += xb * qv4.z; acc[1][3] += xb * qv4.w;
            }
        }
    }
    {
        float* Yp = XY + (size_t)s * BB * C;
        *reinterpret_cast<float4*>(Yp + (2*bp    ) * C + 4 * u) =
            make_float4(acc[0][0], acc[0][1], acc[0][2], acc[0][3]);
        *reinterpret_cast<float4*>(Yp + (2*bp + 1) * C + 4 * u) =
            make_float4(acc[1][0], acc[1][1], acc[1][2], acc[1][3]);
    }
}

__global__ __launch_bounds__(256) void qr64(const float* __restrict__ W,
                                            float* __restrict__ XY) {
    qr_body<64, 16, 64>(W, XY);
}

// ===========================================================================
// C=256 left-looking 2-panel MGS, K=2 columns retired per barrier round.
//   rb = t&15: lane's 16 rows; cb = t>>4: owns panel cols {2cb, 2cb+1}
//   u = t&63 -> apply cols 4u..4u+3; v = t>>6 -> apply rows 2v, 2v+1
// ===========================================================================

// dot + update both register cols against q_j from LDS (R7 op order).
__device__ __forceinline__ void dot_upd(float (&a)[2][16], const float* qpan,
                                        int j, int rb) {
    const float4 q40 = *reinterpret_cast<const float4*>(&qpan[qoff(j, 0, rb)]);
    const float4 q41 = *reinterpret_cast<const float4*>(&qpan[qoff(j, 1, rb)]);
    const float4 q42 = *reinterpret_cast<const float4*>(&qpan[qoff(j, 2, rb)]);
    const float4 q43 = *reinterpret_cast<const float4*>(&qpan[qoff(j, 3, rb)]);
    float p0 = 0.f, p1 = 0.f;
    p0 += a[0][ 0]*q40.x; p1 += a[1][ 0]*q40.x;
    p0 += a[0][ 1]*q40.y; p1 += a[1][ 1]*q40.y;
    p0 += a[0][ 2]*q40.z; p1 += a[1][ 2]*q40.z;
    p0 += a[0][ 3]*q40.w; p1 += a[1][ 3]*q40.w;
    p0 += a[0][ 4]*q41.x; p1 += a[1][ 4]*q41.x;
    p0 += a[0][ 5]*q41.y; p1 += a[1][ 5]*q41.y;
    p0 += a[0][ 6]*q41.z; p1 += a[1][ 6]*q41.z;
    p0 += a[0][ 7]*q41.w; p1 += a[1][ 7]*q41.w;
    p0 += a[0][ 8]*q42.x; p1 += a[1][ 8]*q42.x;
    p0 += a[0][ 9]*q42.y; p1 += a[1][ 9]*q42.y;
    p0 += a[0][10]*q42.z; p1 += a[1][10]*q42.z;
    p0 += a[0][11]*q42.w; p1 += a[1][11]*q42.w;
    p0 += a[0][12]*q43.x; p1 += a[1][12]*q43.x;
    p0 += a[0][13]*q43.y; p1 += a[1][13]*q43.y;
    p0 += a[0][14]*q43.z; p1 += a[1][14]*q43.z;
    p0 += a[0][15]*q43.w; p1 += a[1][15]*q43.w;
    p0 = rowred16(p0); p1 = rowred16(p1);
    a[0][ 0] -= p0*q40.x; a[0][ 1] -= p0*q40.y;
    a[0][ 2] -= p0*q40.z; a[0][ 3] -= p0*q40.w;
    a[0][ 4] -= p0*q41.x; a[0][ 5] -= p0*q41.y;
    a[0][ 6] -= p0*q41.z; a[0][ 7] -= p0*q41.w;
    a[0][ 8] -= p0*q42.x; a[0][ 9] -= p0*q42.y;
    a[0][10] -= p0*q42.z; a[0][11] -= p0*q42.w;
    a[0][12] -= p0*q43.x; a[0][13] -= p0*q43.y;
    a[0][14] -= p0*q43.z; a[0][15] -= p0*q43.w;
    a[1][ 0] -= p1*q40.x; a[1][ 1] -= p1*q40.y;
    a[1][ 2] -= p1*q40.z; a[1][ 3] -= p1*q40.w;
    a[1][ 4] -= p1*q41.x; a[1][ 5] -= p1*q41.y;
    a[1][ 6] -= p1*q41.z; a[1][ 7] -= p1*q41.w;
    a[1][ 8] -= p1*q42.x; a[1][ 9] -= p1*q42.y;
    a[1][10] -= p1*q42.z; a[1][11] -= p1*q42.w;
    a[1][12] -= p1*q43.x; a[1][13] -= p1*q43.y;
    a[1][14] -= p1*q43.z; a[1][15] -= p1*q43.w;
}

// Finish this group's column pair entirely in registers:
// norm .x -> qpan[jx]; orth .y vs scaled .x; norm .y -> qpan[jx+1].
// Op order matches R7's owner paths exactly.
__device__ __forceinline__ void mini_mgs2(float (&a)[2][16], float* qpan,
                                          int jx, int rb) {
    float p = 0.f;
    #pragma unroll
    for (int i = 0; i < 16; ++i) p += a[0][i] * a[0][i];
    p = rowred16(p);
    float rn = 1.0f / sqrtf(p);
    #pragma unroll
    for (int i = 0; i < 16; ++i) a[0][i] *= rn;
    #pragma unroll
    for (int g = 0; g < 4; ++g) {
        *reinterpret_cast<float4*>(&qpan[qoff(jx, g, rb)]) =
            make_float4(a[0][4*g], a[0][4*g+1], a[0][4*g+2], a[0][4*g+3]);
    }
    // orth .y against q_jx (same values as the LDS copy, read from regs)
    float q = 0.f;
    #pragma unroll
    for (int i = 0; i < 16; ++i) q += a[1][i] * a[0][i];
    q = rowred16(q);
    #pragma unroll
    for (int i = 0; i < 16; ++i) a[1][i] -= q * a[0][i];
    // norm .y
    p = 0.f;
    #pragma unroll
    for (int i = 0; i < 16; ++i) p += a[1][i] * a[1][i];
    p = rowred16(p);
    rn = 1.0f / sqrtf(p);
    #pragma unroll
    for (int i = 0; i < 16; ++i) a[1][i] *= rn;
    #pragma unroll
    for (int g = 0; g < 4; ++g) {
        *reinterpret_cast<float4*>(&qpan[qoff(jx + 1, g, rb)]) =
            make_float4(a[1][4*g], a[1][4*g+1], a[1][4*g+2], a[1][4*g+3]);
    }
}

// fused rank-1 apply for col j (R7 op order, j ascending across calls)
__device__ __forceinline__ void apply1(float (&y0)[4], float (&y1)[4],
                                       const float* qpan, const float* xsb,
                                       int j, int u, int v) {
    float4 q4 = *reinterpret_cast<const float4*>(&qpan[qoff(j, u & 3, u >> 2)]);
    const float xa = xsb[j*33 + 2*v];
    const float xb = xsb[j*33 + 2*v + 1];
    y0[0] += xa*q4.x; y0[1] += xa*q4.y; y0[2] += xa*q4.z; y0[3] += xa*q4.w;
    y1[0] += xb*q4.x; y1[1] += xb*q4.y; y1[2] += xb*q4.z; y1[3] += xb*q4.w;
}

__device__ void panel_mgs(float (&a)[2][16], float (&y0)[4], float (&y1)[4],
                          float* qpan, const float* xsb,
                          int rb, int cb, int u, int v) {
    // prologue: group 0 finishes cols 0,1 in-registers (others wait)
    if (cb == 0) mini_mgs2(a, qpan, 0, rb);
    __syncthreads();   // also orders xsb staging / qpan prologue writes
    #pragma unroll 1
    for (int m = 0; m < 64; ++m) {
        // apply first: independent post-barrier work (fills q-read latency)
        apply1(y0, y1, qpan, xsb, 2*m,     u, v);
        apply1(y0, y1, qpan, xsb, 2*m + 1, u, v);
        if (cb > m) {
            dot_upd(a, qpan, 2*m,     rb);
            dot_upd(a, qpan, 2*m + 1, rb);
            if (cb == m + 1) mini_mgs2(a, qpan, 2*m + 2, rb);
        }
        __syncthreads();
    }
}

__global__ __launch_bounds__(1024) void qr256ll(const float* __restrict__ W,
                                                float* __restrict__ XY) {
    __shared__ float qpan[128 * 256];   // 128 KiB: finished q's, 1KB/col slot
    __shared__ float xsb[128 * 33];     // 16.5 KiB: X panel [col][b], pad 33

    const int s  = blockIdx.x;
    const int t  = threadIdx.x;
    const int rb = t & 15;
    const int cb = t >> 4;
    const int u  = t & 63;
    const int v  = t >> 6;

    const float* Wp = W + (size_t)s * 65536;
    float* Xp = XY + (size_t)s * 8192;

    float a[2][16];
    float y0[4] = {0,0,0,0};
    float y1[4] = {0,0,0,0};

    // ---- panel 0: load W cols [0,128) + stage X cols [0,128) ----
    #pragma unroll
    for (int i = 0; i < 16; ++i) {
        float2 w2 = *reinterpret_cast<const float2*>(
            Wp + (size_t)(rb*16 + i) * 256 + 2*cb);
        a[0][i] = w2.x; a[1][i] = w2.y;
    }
    {
        const int tj = t & 127, tb = t >> 7;
        #pragma unroll
        for (int d = 0; d < 4; ++d)
            xsb[tj*33 + 4*tb + d] = Xp[(4*tb + d)*256 + tj];
    }
    // (no barrier needed here: panel_mgs's prologue barrier orders everything)
    panel_mgs(a, y0, y1, qpan, xsb, rb, cb, u, v);

    // ---- glue: reload regs with W cols [128,256), restage X, cross-pass ----
    __syncthreads();   // panel-0 consumers done before xsb is overwritten
    #pragma unroll
    for (int i = 0; i < 16; ++i) {
        float2 w2 = *reinterpret_cast<const float2*>(
            Wp + (size_t)(rb*16 + i) * 256 + 128 + 2*cb);
        a[0][i] = w2.x; a[1][i] = w2.y;
    }
    {
        const int tj = t & 127, tb = t >> 7;
        #pragma unroll
        for (int d = 0; d < 4; ++d)
            xsb[tj*33 + 4*tb + d] = Xp[(4*tb + d)*256 + 128 + tj];
    }
    // cross-pass: orthogonalize both register cols vs Q0 (barrier-free;
    // qpan read-only here, xsb writes touch a disjoint region)
    #pragma unroll 1
    for (int k = 0; k < 128; ++k) {
        dot_upd(a, qpan, k, rb);
    }
    __syncthreads();   // cross-pass done everywhere before qpan[0,1] overwrite

    // ---- panel 1 (qpan slots reused; Q0 no longer needed) ----
    panel_mgs(a, y0, y1, qpan, xsb, rb, cb, u, v);

    // ---- write Y in place over X (coalesced float4) ----
    *reinterpret_cast<float4*>(Xp + (size_t)(2*v    )*256 + 4*u) =
        make_float4(y0[0], y0[1], y0[2], y0[3]);
    *reinterpret_cast<float4*>(Xp + (size_t)(2*v + 1)*256 + 4*u) =
        make_float4(y1[0], y1[1], y1[2], y1[3]);
}

extern "C" void kernel_launch(void* const* d_in, const int* in_sizes, int n_in,
                              void* d_out, int out_size, void* d_ws, size_t ws_size,
                              hipStream_t stream) {
    (void)in_sizes; (void)n_in; (void)out_size; (void)ws_size;
    const float* x0 = (const float*)d_in[0];  // (32, 64, 784)
    const float* x1 = (const float*)d_in[1];  // (32, 256, 196)
    const float* W0 = (const float*)d_in[2];  // (784, 64, 64)
    const float* W1 = (const float*)d_in[3];  // (196, 256, 256)
    float* y0  = (float*)d_out;               // (32, 64, 784) flat
    float* y1  = y0 + 1605632;                // (32, 256, 196) flat
    float* xt0 = (float*)d_ws;                // (784, 32*64)
    float* xt1 = xt0 + 1605632;               // (196, 32*256)

    dim3 tb(32, 8);
    // x (B*C, S) -> xt (S, B*C)
    tkern<<<dim3(25,  64), tb, 0, stream>>>(x0, xt0, 2048, 784);
    tkern<<<dim3(7,  256), tb, 0, stream>>>(x1, xt1, 8192, 196);
    // fused QR + apply (Y overwrites xt in place)
    qr64   <<<784,  256, 0, stream>>>(W0, xt0);
    qr256ll<<<196, 1024, 0, stream>>>(W1, xt1);
    // xt (S, B*C) -> y (B*C, S)
    tkern<<<dim3(64,  25), tb, 0, stream>>>(xt0, y0, 784, 2048);
    tkern<<<dim3(256,  7), tb, 0, stream>>>(xt1, y1, 196, 8192);
}

// Round 10
// 288.733 us; speedup vs baseline: 1.2842x; 1.0054x over previous
//
#include <hip/hip_runtime.h>

// ---------------------------------------------------------------------------
// TopoTransform: batched sign-fixed QR (MGS) + per-site channel mix.
//   problem 0: B=32, C=64,  S=784   problem 1: B=32, C=256, S=196
//   out[b][c][s] = sum_k Q[s][c][k] * x[b][k][s],  Q[s] = qr(W[s]) sign-fixed
// MGS yields R[j][j] > 0 directly => Q already sign-fixed.
//
// R10: R9 structure (2 cols retired per barrier round) + sched_barrier(0)
// fences at region boundaries in the round body and cross-pass. R9 evidence:
// round-halving helped (291->255us) but WRITE_SIZE 6272->17248 KB = the
// scheduler co-hoisted apply/dot_upd/dot_upd LDS loads across call
// boundaries (~78 live regs > 64 budget) -> ~14 floats/thread scratch
// round-trip EVERY round. Fences cap liveness at ~62 while leaving
// within-region scheduling (16-reg q CSE, DS latency hiding) intact.
// No arithmetic change -> absmax must stay EXACTLY 0.09765625; spill
// sentinel: WRITE_SIZE must return to 6272 KB.
// ---------------------------------------------------------------------------

static constexpr int BB = 32;  // batch

#define SCHED_FENCE() __builtin_amdgcn_sched_barrier(0)

// -------- DPP 16-lane all-reduce (sum) on the VALU pipe --------------------
template<int CTRL>
__device__ __forceinline__ float dpp_add(float x) {
    int y = __builtin_amdgcn_update_dpp(0, __float_as_int(x), CTRL, 0xF, 0xF, false);
    return x + __int_as_float(y);
}
__device__ __forceinline__ float rowred16(float p) {
    p = dpp_add<0x128>(p);  // row_ror:8
    p = dpp_add<0x124>(p);  // row_ror:4
    p = dpp_add<0x122>(p);  // row_ror:2
    p = dpp_add<0x121>(p);  // row_ror:1
    return p;               // all 16 lanes of the row hold the sum
}

// qpan slot layout (1KB per col j): row r = r16*16 + 4g + e stored at
// float idx j*256 + g*64 + ((r16 ^ 2g) << 2) + e.
__device__ __forceinline__ int qoff(int j, int g, int r16) {
    return j * 256 + g * 64 + ((r16 ^ (2 * g)) << 2);
}

// -------- transpose: in (R, S) row-major -> out (S, R) row-major ----------
__global__ __launch_bounds__(256) void tkern(const float* __restrict__ in,
                                             float* __restrict__ out,
                                             int R, int S) {
    __shared__ float tile[32][33];
    const int tx = threadIdx.x, ty = threadIdx.y;
    const int s0 = blockIdx.x * 32, r0 = blockIdx.y * 32;
    #pragma unroll
    for (int i = ty; i < 32; i += 8) {
        int r = r0 + i, s = s0 + tx;
        tile[i][tx] = (r < R && s < S) ? in[(size_t)r * S + s] : 0.f;
    }
    __syncthreads();
    #pragma unroll
    for (int i = ty; i < 32; i += 8) {
        int s = s0 + i, r = r0 + tx;
        if (s < S && r < R) out[(size_t)s * R + r] = tile[tx][i];
    }
}

// ===========================================================================
// C=64 path: unchanged (register-resident MGS + chunked apply).
// ===========================================================================
template<int C, int CT, int KC>
__device__ __forceinline__ void qr_body(const float* __restrict__ W,
                                        float* __restrict__ XY) {
    constexpr int RT = 16;
    constexpr int TR = C / RT;
    constexpr int THREADS = RT * CT;
    constexpr int QSTR = TR + 4;
    constexpr int XSTR = C + 4;

    const int s  = blockIdx.x;
    const int t  = threadIdx.x;
    const int rb = t & 15;
    const int cb = t >> 4;

    __shared__ float qs[2][RT * QSTR];
    __shared__ float xs[BB * XSTR];
    __shared__ float qc[KC * C];

    float a[TR][4];
    {
        const float* Wp = W + (size_t)s * C * C + (size_t)(rb * TR) * C + cb * 4;
        #pragma unroll
        for (int i = 0; i < TR; ++i) {
            float4 v = *reinterpret_cast<const float4*>(Wp + (size_t)i * C);
            a[i][0] = v.x; a[i][1] = v.y; a[i][2] = v.z; a[i][3] = v.w;
        }
    }
    {
        const float* Xp = XY + (size_t)s * BB * C;
        #pragma unroll
        for (int v = 0; v < (BB * C) / (4 * THREADS); ++v) {
            int idx = 4 * (t + v * THREADS);
            int b = idx / C, k = idx % C;
            float4 x4 = *reinterpret_cast<const float4*>(Xp + idx);
            *reinterpret_cast<float4*>(&xs[b * XSTR + k]) = x4;
        }
    }

    int buf = 0;
    #pragma unroll 1
    for (int j = 0; j < C; ++j) {
        const int cbj = j >> 2, jj = j & 3;
        if (cb == cbj) {
            #pragma unroll
            for (int q = 0; q < 4; ++q) {
                if (q == jj) {
                    float p = 0.f;
                    #pragma unroll
                    for (int i = 0; i < TR; ++i) p += a[i][q] * a[i][q];
                    p = rowred16(p);
                    const float rn = 1.0f / sqrtf(p);
                    #pragma unroll
                    for (int i = 0; i < TR; ++i) a[i][q] *= rn;
                    #pragma unroll
                    for (int i = 0; i < TR; i += 4) {
                        *reinterpret_cast<float4*>(&qs[buf][rb * QSTR + i]) =
                            make_float4(a[i][q], a[i+1][q], a[i+2][q], a[i+3][q]);
                    }
                }
            }
        }
        __syncthreads();
        if (cb * 4 + 3 > j) {
            float qv[TR];
            #pragma unroll
            for (int i = 0; i < TR; i += 4) {
                float4 v = *reinterpret_cast<const float4*>(&qs[buf][rb * QSTR + i]);
                qv[i] = v.x; qv[i+1] = v.y; qv[i+2] = v.z; qv[i+3] = v.w;
            }
            #pragma unroll
            for (int q = 0; q < 4; ++q) {
                if (cb * 4 + q > j) {
                    float p = 0.f;
                    #pragma unroll
                    for (int i = 0; i < TR; ++i) p += a[i][q] * qv[i];
                    p = rowred16(p);
                    #pragma unroll
                    for (int i = 0; i < TR; ++i) a[i][q] -= p * qv[i];
                }
            }
        }
        buf ^= 1;
    }

    const int u  = t % (C / 4);
    const int bp = t / (C / 4);
    float acc[2][4] = {{0,0,0,0},{0,0,0,0}};

    #pragma unroll 1
    for (int ch = 0; ch < C / KC; ++ch) {
        __syncthreads();
        if (cb >= (ch * KC) / 4 && cb < ((ch + 1) * KC) / 4) {
            #pragma unroll
            for (int q = 0; q < 4; ++q) {
                const int kk = cb * 4 + q - ch * KC;
                const int swz = (kk & 7) << 2;
                #pragma unroll
                for (int i = 0; i < TR; i += 4) {
                    const int cout = rb * TR + i;
                    *reinterpret_cast<float4*>(&qc[kk * C + (cout ^ swz)]) =
                        make_float4(a[i][q], a[i+1][q], a[i+2][q], a[i+3][q]);
                }
            }
        }
        __syncthreads();
        #pragma unroll
        for (int kk = 0; kk < KC; kk += 4) {
            const int k = ch * KC + kk;
            float4 x0 = *reinterpret_cast<const float4*>(&xs[(2*bp    ) * XSTR + k]);
            float4 x1 = *reinterpret_cast<const float4*>(&xs[(2*bp + 1) * XSTR + k]);
            #pragma unroll
            for (int m = 0; m < 4; ++m) {
                const int swz = ((kk + m) & 7) << 2;
                float4 qv4 = *reinterpret_cast<const float4*>(&qc[(kk + m) * C + ((4 * u) ^ swz)]);
                const float xa = (&x0.x)[m], xb = (&x1.x)[m];
                acc[0][0] += xa * qv4.x; acc[0][1] += xa * qv4.y;
                acc[0][2] += xa * qv4.z; acc[0][3] += xa * qv4.w;
                acc[1][0] += xb * qv4.x; acc[1][1] += xb * qv4.y;
                acc[1][2] += xb * qv4.z; acc[1][3] += xb * qv4.w;
            }
        }
    }
    {
        float* Yp = XY + (size_t)s * BB * C;
        *reinterpret_cast<float4*>(Yp + (2*bp    ) * C + 4 * u) =
            make_float4(acc[0][0], acc[0][1], acc[0][2], acc[0][3]);
        *reinterpret_cast<float4*>(Yp + (2*bp + 1) * C + 4 * u) =
            make_float4(acc[1][0], acc[1][1], acc[1][2], acc[1][3]);
    }
}

__global__ __launch_bounds__(256) void qr64(const float* __restrict__ W,
                                            float* __restrict__ XY) {
    qr_body<64, 16, 64>(W, XY);
}

// ===========================================================================
// C=256 left-looking 2-panel MGS, K=2 columns retired per barrier round.
//   rb = t&15: lane's 16 rows; cb = t>>4: owns panel cols {2cb, 2cb+1}
//   u = t&63 -> apply cols 4u..4u+3; v = t>>6 -> apply rows 2v, 2v+1
// ===========================================================================

// dot + update both register cols against q_j from LDS (R7 op order).
__device__ __forceinline__ void dot_upd(float (&a)[2][16], const float* qpan,
                                        int j, int rb) {
    const float4 q40 = *reinterpret_cast<const float4*>(&qpan[qoff(j, 0, rb)]);
    const float4 q41 = *reinterpret_cast<const float4*>(&qpan[qoff(j, 1, rb)]);
    const float4 q42 = *reinterpret_cast<const float4*>(&qpan[qoff(j, 2, rb)]);
    const float4 q43 = *reinterpret_cast<const float4*>(&qpan[qoff(j, 3, rb)]);
    float p0 = 0.f, p1 = 0.f;
    p0 += a[0][ 0]*q40.x; p1 += a[1][ 0]*q40.x;
    p0 += a[0][ 1]*q40.y; p1 += a[1][ 1]*q40.y;
    p0 += a[0][ 2]*q40.z; p1 += a[1][ 2]*q40.z;
    p0 += a[0][ 3]*q40.w; p1 += a[1][ 3]*q40.w;
    p0 += a[0][ 4]*q41.x; p1 += a[1][ 4]*q41.x;
    p0 += a[0][ 5]*q41.y; p1 += a[1][ 5]*q41.y;
    p0 += a[0][ 6]*q41.z; p1 += a[1][ 6]*q41.z;
    p0 += a[0][ 7]*q41.w; p1 += a[1][ 7]*q41.w;
    p0 += a[0][ 8]*q42.x; p1 += a[1][ 8]*q42.x;
    p0 += a[0][ 9]*q42.y; p1 += a[1][ 9]*q42.y;
    p0 += a[0][10]*q42.z; p1 += a[1][10]*q42.z;
    p0 += a[0][11]*q42.w; p1 += a[1][11]*q42.w;
    p0 += a[0][12]*q43.x; p1 += a[1][12]*q43.x;
    p0 += a[0][13]*q43.y; p1 += a[1][13]*q43.y;
    p0 += a[0][14]*q43.z; p1 += a[1][14]*q43.z;
    p0 += a[0][15]*q43.w; p1 += a[1][15]*q43.w;
    p0 = rowred16(p0); p1 = rowred16(p1);
    a[0][ 0] -= p0*q40.x; a[0][ 1] -= p0*q40.y;
    a[0][ 2] -= p0*q40.z; a[0][ 3] -= p0*q40.w;
    a[0][ 4] -= p0*q41.x; a[0][ 5] -= p0*q41.y;
    a[0][ 6] -= p0*q41.z; a[0][ 7] -= p0*q41.w;
    a[0][ 8] -= p0*q42.x; a[0][ 9] -= p0*q42.y;
    a[0][10] -= p0*q42.z; a[0][11] -= p0*q42.w;
    a[0][12] -= p0*q43.x; a[0][13] -= p0*q43.y;
    a[0][14] -= p0*q43.z; a[0][15] -= p0*q43.w;
    a[1][ 0] -= p1*q40.x; a[1][ 1] -= p1*q40.y;
    a[1][ 2] -= p1*q40.z; a[1][ 3] -= p1*q40.w;
    a[1][ 4] -= p1*q41.x; a[1][ 5] -= p1*q41.y;
    a[1][ 6] -= p1*q41.z; a[1][ 7] -= p1*q41.w;
    a[1][ 8] -= p1*q42.x; a[1][ 9] -= p1*q42.y;
    a[1][10] -= p1*q42.z; a[1][11] -= p1*q42.w;
    a[1][12] -= p1*q43.x; a[1][13] -= p1*q43.y;
    a[1][14] -= p1*q43.z; a[1][15] -= p1*q43.w;
}

// Finish this group's column pair entirely in registers:
// norm .x -> qpan[jx]; orth .y vs scaled .x; norm .y -> qpan[jx+1].
__device__ __forceinline__ void mini_mgs2(float (&a)[2][16], float* qpan,
                                          int jx, int rb) {
    float p = 0.f;
    #pragma unroll
    for (int i = 0; i < 16; ++i) p += a[0][i] * a[0][i];
    p = rowred16(p);
    float rn = 1.0f / sqrtf(p);
    #pragma unroll
    for (int i = 0; i < 16; ++i) a[0][i] *= rn;
    #pragma unroll
    for (int g = 0; g < 4; ++g) {
        *reinterpret_cast<float4*>(&qpan[qoff(jx, g, rb)]) =
            make_float4(a[0][4*g], a[0][4*g+1], a[0][4*g+2], a[0][4*g+3]);
    }
    // orth .y against q_jx (same values as the LDS copy, read from regs)
    float q = 0.f;
    #pragma unroll
    for (int i = 0; i < 16; ++i) q += a[1][i] * a[0][i];
    q = rowred16(q);
    #pragma unroll
    for (int i = 0; i < 16; ++i) a[1][i] -= q * a[0][i];
    // norm .y
    p = 0.f;
    #pragma unroll
    for (int i = 0; i < 16; ++i) p += a[1][i] * a[1][i];
    p = rowred16(p);
    rn = 1.0f / sqrtf(p);
    #pragma unroll
    for (int i = 0; i < 16; ++i) a[1][i] *= rn;
    #pragma unroll
    for (int g = 0; g < 4; ++g) {
        *reinterpret_cast<float4*>(&qpan[qoff(jx + 1, g, rb)]) =
            make_float4(a[1][4*g], a[1][4*g+1], a[1][4*g+2], a[1][4*g+3]);
    }
}

// fused rank-1 apply for col j (j ascending across calls)
__device__ __forceinline__ void apply1(float (&y0)[4], float (&y1)[4],
                                       const float* qpan, const float* xsb,
                                       int j, int u, int v) {
    float4 q4 = *reinterpret_cast<const float4*>(&qpan[qoff(j, u & 3, u >> 2)]);
    const float xa = xsb[j*33 + 2*v];
    const float xb = xsb[j*33 + 2*v + 1];
    y0[0] += xa*q4.x; y0[1] += xa*q4.y; y0[2] += xa*q4.z; y0[3] += xa*q4.w;
    y1[0] += xb*q4.x; y1[1] += xb*q4.y; y1[2] += xb*q4.z; y1[3] += xb*q4.w;
}

__device__ void panel_mgs(float (&a)[2][16], float (&y0)[4], float (&y1)[4],
                          float* qpan, const float* xsb,
                          int rb, int cb, int u, int v) {
    // prologue: group 0 finishes cols 0,1 in-registers (others wait)
    if (cb == 0) mini_mgs2(a, qpan, 0, rb);
    __syncthreads();   // also orders xsb staging / qpan prologue writes
    #pragma unroll 1
    for (int m = 0; m < 64; ++m) {
        // apply first: independent post-barrier work (fills q-read latency)
        apply1(y0, y1, qpan, xsb, 2*m,     u, v);
        apply1(y0, y1, qpan, xsb, 2*m + 1, u, v);
        SCHED_FENCE();   // cap liveness: apply regs retire before dot phase
        if (cb > m) {
            dot_upd(a, qpan, 2*m,     rb);
            SCHED_FENCE();   // no cross-call q-load hoisting (R9 spill cause)
            dot_upd(a, qpan, 2*m + 1, rb);
            SCHED_FENCE();
            if (cb == m + 1) mini_mgs2(a, qpan, 2*m + 2, rb);
        }
        __syncthreads();
    }
}

__global__ __launch_bounds__(1024) void qr256ll(const float* __restrict__ W,
                                                float* __restrict__ XY) {
    __shared__ float qpan[128 * 256];   // 128 KiB: finished q's, 1KB/col slot
    __shared__ float xsb[128 * 33];     // 16.5 KiB: X panel [col][b], pad 33

    const int s  = blockIdx.x;
    const int t  = threadIdx.x;
    const int rb = t & 15;
    const int cb = t >> 4;
    const int u  = t & 63;
    const int v  = t >> 6;

    const float* Wp = W + (size_t)s * 65536;
    float* Xp = XY + (size_t)s * 8192;

    float a[2][16];
    float y0[4] = {0,0,0,0};
    float y1[4] = {0,0,0,0};

    // ---- panel 0: load W cols [0,128) + stage X cols [0,128) ----
    #pragma unroll
    for (int i = 0; i < 16; ++i) {
        float2 w2 = *reinterpret_cast<const float2*>(
            Wp + (size_t)(rb*16 + i) * 256 + 2*cb);
        a[0][i] = w2.x; a[1][i] = w2.y;
    }
    {
        const int tj = t & 127, tb = t >> 7;
        #pragma unroll
        for (int d = 0; d < 4; ++d)
            xsb[tj*33 + 4*tb + d] = Xp[(4*tb + d)*256 + tj];
    }
    // (no barrier needed here: panel_mgs's prologue barrier orders everything)
    panel_mgs(a, y0, y1, qpan, xsb, rb, cb, u, v);

    // ---- glue: reload regs with W cols [128,256), restage X, cross-pass ----
    __syncthreads();   // panel-0 consumers done before xsb is overwritten
    #pragma unroll
    for (int i = 0; i < 16; ++i) {
        float2 w2 = *reinterpret_cast<const float2*>(
            Wp + (size_t)(rb*16 + i) * 256 + 128 + 2*cb);
        a[0][i] = w2.x; a[1][i] = w2.y;
    }
    {
        const int tj = t & 127, tb = t >> 7;
        #pragma unroll
        for (int d = 0; d < 4; ++d)
            xsb[tj*33 + 4*tb + d] = Xp[(4*tb + d)*256 + 128 + tj];
    }
    // cross-pass: orthogonalize both register cols vs Q0 (barrier-free;
    // qpan read-only here, xsb writes touch a disjoint region)
    #pragma unroll 1
    for (int k = 0; k < 128; ++k) {
        dot_upd(a, qpan, k, rb);
        SCHED_FENCE();   // no next-k q-load pipelining into current compute
    }
    __syncthreads();   // cross-pass done everywhere before qpan[0,1] overwrite

    // ---- panel 1 (qpan slots reused; Q0 no longer needed) ----
    panel_mgs(a, y0, y1, qpan, xsb, rb, cb, u, v);

    // ---- write Y in place over X (coalesced float4) ----
    *reinterpret_cast<float4*>(Xp + (size_t)(2*v    )*256 + 4*u) =
        make_float4(y0[0], y0[1], y0[2], y0[3]);
    *reinterpret_cast<float4*>(Xp + (size_t)(2*v + 1)*256 + 4*u) =
        make_float4(y1[0], y1[1], y1[2], y1[3]);
}

extern "C" void kernel_launch(void* const* d_in, const int* in_sizes, int n_in,
                              void* d_out, int out_size, void* d_ws, size_t ws_size,
                              hipStream_t stream) {
    (void)in_sizes; (void)n_in; (void)out_size; (void)ws_size;
    const float* x0 = (const float*)d_in[0];  // (32, 64, 784)
    const float* x1 = (const float*)d_in[1];  // (32, 256, 196)
    const float* W0 = (const float*)d_in[2];  // (784, 64, 64)
    const float* W1 = (const float*)d_in[3];  // (196, 256, 256)
    float* y0  = (float*)d_out;               // (32, 64, 784) flat
    float* y1  = y0 + 1605632;                // (32, 256, 196) flat
    float* xt0 = (float*)d_ws;                // (784, 32*64)
    float* xt1 = xt0 + 1605632;               // (196, 32*256)

    dim3 tb(32, 8);
    // x (B*C, S) -> xt (S, B*C)
    tkern<<<dim3(25,  64), tb, 0, stream>>>(x0, xt0, 2048, 784);
    tkern<<<dim3(7,  256), tb, 0, stream>>>(x1, xt1, 8192, 196);
    // fused QR + apply (Y overwrites xt in place)
    qr64   <<<784,  256, 0, stream>>>(W0, xt0);
    qr256ll<<<196, 1024, 0, stream>>>(W1, xt1);
    // xt (S, B*C) -> y (B*C, S)
    tkern<<<dim3(64,  25), tb, 0, stream>>>(xt0, y0, 784, 2048);
    tkern<<<dim3(256,  7), tb, 0, stream>>>(xt1, y1, 196, 8192);
}